// Round 3
// baseline (70.905 us; speedup 1.0000x reference)
//
#include <hip/hip_runtime.h>

#define D 32
#define H 128

// ---------------- Kernel 1: metric only ----------------
// grid = 32 (one block per batch), block = 256
__global__ __launch_bounds__(256) void metric_kernel(
    const float* __restrict__ points,
    const float* __restrict__ mw1, const float* __restrict__ mb1,
    const float* __restrict__ mw2, const float* __restrict__ mb2,
    float* __restrict__ metric)
{
    __shared__ float p[D];
    __shared__ float h1[H];
    const int b = blockIdx.x;
    const int t = threadIdx.x;
    if (t < D) p[t] = points[b * D + t];
    __syncthreads();

    if (t < H) {
        float acc = mb1[t];
        #pragma unroll
        for (int d = 0; d < D; ++d) acc = fmaf(p[d], mw1[d * H + t], acc);
        h1[t] = fmaxf(acc, 0.0f);
    }
    __syncthreads();

    #pragma unroll
    for (int q = 0; q < 4; ++q) {
        const int m = q * 256 + t;
        float acc = mb2[m];
        for (int h = 0; h < H; ++h) acc = fmaf(h1[h], mw2[h * 1024 + m], acc);
        metric[b * 1024 + m] = acc;
    }
}

// ---------------- Kernel 2: fused christoffel + ricci ----------------
// Block = (b,i). Phase 1: per-block bases (cbase/rbase/sumw, cheap, redundant).
// Phase 2: christoffel for all 1024 (j,k) rows -> Gs in LDS (never global).
// Phase 3: ricci reduction for 32 outputs.
// tanh(x) = 1 - 2*rcp(exp2(Kc*x)+1); Kc=2*log2(e) folded into pack;
// sum_h cw2*tanh = sum(cw2) + sum_h (-2*cw2[h])*rcp_h -> 4 VALU + 2 trans/eval.
// grid = 1024, block = 256
__global__ __launch_bounds__(256) void fused_kernel(
    const float* __restrict__ points, const float* __restrict__ metric,
    const float* __restrict__ cw1, const float* __restrict__ cb1,
    const float* __restrict__ cw2, const float* __restrict__ cb2,
    const float* __restrict__ rw1, const float* __restrict__ rb1,
    const float* __restrict__ rw2, const float* __restrict__ rb2,
    float* __restrict__ out)
{
    __shared__ float p[D];
    __shared__ float M[D * D];          // metric[b], 4 KB
    __shared__ float4 pack[H];          // {Kc*cbase, Kc*a1, Kc*a2, Kc*a3}
    __shared__ float wm2[H];            // -2*cw2
    __shared__ float Gs[D * D];         // gamma[b,i,:,:], 4 KB, never leaves LDS
    __shared__ float red[4][D];
    __shared__ float sumw_s;

    const int bi = blockIdx.x;
    const int b  = bi >> 5;
    const int i  = bi & 31;
    const int t  = threadIdx.x;

    // ricci weights for hidden unit t: issue global loads early (L2-hit after warmup)
    float w[33];
    #pragma unroll
    for (int f = 0; f < 33; ++f) w[f] = rw1[(32 + f) * 256 + t];
    const float wo    = rw2[t];
    const float rbias = rb2[0];

    if (t < D) p[t] = points[b * D + t];
    #pragma unroll
    for (int q = 0; q < 4; ++q) M[q * 256 + t] = metric[b * 1024 + q * 256 + t];
    __syncthreads();

    // ---- Phase 1: per-block bases ----
    if (t < H) {
        constexpr float Kc = 2.8853900817779268f;   // 2*log2(e)
        float cacc = cb1[t];
        #pragma unroll
        for (int d = 0; d < D; ++d) cacc = fmaf(p[d], cw1[d * H + t], cacc);
        pack[t] = make_float4(Kc * cacc,
                              Kc * cw1[32 * H + t],
                              Kc * cw1[33 * H + t],
                              Kc * cw1[34 * H + t]);
        wm2[t] = -2.0f * cw2[t];
    }
    float rbv = rb1[t];
    #pragma unroll
    for (int d = 0; d < D; ++d) rbv = fmaf(p[d], rw1[d * 256 + t], rbv);
    if (t < 64) {
        float v = cw2[t] + cw2[t + 64];
        #pragma unroll
        for (int off = 32; off > 0; off >>= 1) v += __shfl_xor(v, off);
        if (t == 0) sumw_s = v;
    }
    __syncthreads();

    // ---- Phase 2: christoffel, 4 rows per thread ----
    const int j  = t >> 3;
    const int k0 = (t & 7) * 4;

    const float gij = M[i * 32 + j];
    float gjk[4], gki[4], acc[4];
    #pragma unroll
    for (int r = 0; r < 4; ++r) {
        gjk[r] = M[j * 32 + k0 + r];
        gki[r] = M[(k0 + r) * 32 + i];
        acc[r] = 0.0f;
    }

    #pragma unroll 8
    for (int h = 0; h < H; ++h) {
        const float4 c = pack[h];
        const float woh = wm2[h];
        const float pre = fmaf(gij, c.y, c.x);
        #pragma unroll
        for (int r = 0; r < 4; ++r) {
            const float x  = fmaf(gki[r], c.w, fmaf(gjk[r], c.z, pre));
            const float e  = __builtin_amdgcn_exp2f(x);
            const float rc = __builtin_amdgcn_rcpf(e + 1.0f);
            acc[r] = fmaf(rc, woh, acc[r]);
        }
    }

    const float addc = sumw_s + cb2[0];
    *((float4*)(Gs + t * 4)) = make_float4(acc[0] + addc, acc[1] + addc,
                                           acc[2] + addc, acc[3] + addc);
    __syncthreads();

    // ---- Phase 3: ricci, thread = hidden unit, zero inner barriers ----
    const int wid  = t >> 6;
    const int lane = t & 63;

    for (int jj = 0; jj < 32; ++jj) {
        float hid = fmaf(M[i * 32 + jj], w[0], rbv);
        #pragma unroll
        for (int k4 = 0; k4 < 8; ++k4) {
            const float4 g = ((float4*)Gs)[jj * 8 + k4];
            hid = fmaf(g.x, w[k4 * 4 + 1], hid);
            hid = fmaf(g.y, w[k4 * 4 + 2], hid);
            hid = fmaf(g.z, w[k4 * 4 + 3], hid);
            hid = fmaf(g.w, w[k4 * 4 + 4], hid);
        }
        float pp = fmaxf(hid, 0.0f) * wo;
        #pragma unroll
        for (int off = 32; off > 0; off >>= 1) pp += __shfl_xor(pp, off);
        if (lane == 0) red[wid][jj] = pp;
    }
    __syncthreads();
    if (t < 32) out[bi * 32 + t] = red[0][t] + red[1][t] + red[2][t] + red[3][t] + rbias;
}

extern "C" void kernel_launch(void* const* d_in, const int* in_sizes, int n_in,
                              void* d_out, int out_size, void* d_ws, size_t ws_size,
                              hipStream_t stream) {
    const float* points = (const float*)d_in[0];
    const float* mw1 = (const float*)d_in[1];
    const float* mb1 = (const float*)d_in[2];
    const float* mw2 = (const float*)d_in[3];
    const float* mb2 = (const float*)d_in[4];
    const float* cw1 = (const float*)d_in[5];
    const float* cb1 = (const float*)d_in[6];
    const float* cw2 = (const float*)d_in[7];
    const float* cb2 = (const float*)d_in[8];
    const float* rw1 = (const float*)d_in[9];
    const float* rb1 = (const float*)d_in[10];
    const float* rw2 = (const float*)d_in[11];
    const float* rb2 = (const float*)d_in[12];
    float* out = (float*)d_out;

    float* metric = (float*)d_ws;   // 32*1024 f32 = 128 KB

    metric_kernel<<<32, 256, 0, stream>>>(points, mw1, mb1, mw2, mb2, metric);
    fused_kernel<<<1024, 256, 0, stream>>>(points, metric,
                                           cw1, cb1, cw2, cb2,
                                           rw1, rb1, rw2, rb2, out);
}

// Round 4
// 65.429 us; speedup vs baseline: 1.0837x; 1.0837x over previous
//
#include <hip/hip_runtime.h>

#define D 32
#define H 128

typedef float v2f __attribute__((ext_vector_type(2)));

// ---------------- Stage A: metric + per-batch MLP bases + folded constants ----------------
// grid = 32 (one block per batch element), block = 256
__global__ __launch_bounds__(256) void setup_kernel(
    const float* __restrict__ points,
    const float* __restrict__ mw1, const float* __restrict__ mb1,
    const float* __restrict__ mw2, const float* __restrict__ mb2,
    const float* __restrict__ cw1, const float* __restrict__ cb1,
    const float* __restrict__ cw2,
    const float* __restrict__ rw1, const float* __restrict__ rb1,
    float* __restrict__ metric, float* __restrict__ cbase, float* __restrict__ rbase,
    float* __restrict__ sumw)
{
    __shared__ float p[D];
    __shared__ float h1[H];
    const int b = blockIdx.x;
    const int t = threadIdx.x;
    if (t < D) p[t] = points[b * D + t];
    __syncthreads();

    if (t < H) {
        float acc = mb1[t];
        #pragma unroll
        for (int d = 0; d < D; ++d) acc = fmaf(p[d], mw1[d * H + t], acc);
        h1[t] = fmaxf(acc, 0.0f);
        float cacc = cb1[t];
        #pragma unroll
        for (int d = 0; d < D; ++d) cacc = fmaf(p[d], cw1[d * H + t], cacc);
        cbase[b * H + t] = cacc;
    }
    {
        float racc = rb1[t];
        #pragma unroll
        for (int d = 0; d < D; ++d) racc = fmaf(p[d], rw1[d * 256 + t], racc);
        rbase[b * 256 + t] = racc;
    }
    if (b == 0 && t < 64) {
        float v = cw2[t] + cw2[t + 64];
        #pragma unroll
        for (int off = 32; off > 0; off >>= 1) v += __shfl_xor(v, off);
        if (t == 0) sumw[0] = v;
    }
    __syncthreads();

    #pragma unroll
    for (int q = 0; q < 4; ++q) {
        const int m = q * 256 + t;
        float acc = mb2[m];
        for (int h = 0; h < H; ++h) acc = fmaf(h1[h], mw2[h * 1024 + m], acc);
        metric[b * 1024 + m] = acc;
    }
}

// ---------------- Stage B: christoffel, 1M rows ----------------
// tanh folded: sum_h cw2*tanh = sum(cw2) + sum_h (-2*cw2[h]) * rcp(exp2(Kc*x)+1).
// 2 rows (adjacent k) per thread, v2f-packed -> v_pk_fma_f32.
// grid = 32*32*2 = 2048 blocks (8 blocks/CU -> 8 waves/SIMD at VGPR<=64), block = 256
__global__ __launch_bounds__(256) void christoffel_kernel(
    const float* __restrict__ metric, const float* __restrict__ cbase,
    const float* __restrict__ cw1, const float* __restrict__ cw2,
    const float* __restrict__ cb2, const float* __restrict__ sumw,
    float* __restrict__ gamma)
{
    __shared__ float M[D * D];          // metric[b], 4 KB
    __shared__ float4 pack[H];          // {Kc*cbase, Kc*a1, Kc*a2, Kc*a3}
    __shared__ float wm2[H];            // -2*cw2
    const int blk = blockIdx.x;
    const int b   = blk >> 6;
    const int i   = (blk >> 1) & 31;
    const int jh  = blk & 1;
    const int t   = threadIdx.x;

    #pragma unroll
    for (int q = 0; q < 4; ++q) M[q * 256 + t] = metric[b * 1024 + q * 256 + t];
    if (t < H) {
        constexpr float Kc = 2.8853900817779268f;   // 2*log2(e)
        pack[t] = make_float4(Kc * cbase[b * H + t],
                              Kc * cw1[32 * H + t],
                              Kc * cw1[33 * H + t],
                              Kc * cw1[34 * H + t]);
        wm2[t] = -2.0f * cw2[t];
    }
    __syncthreads();

    const int j  = jh * 16 + (t >> 4);
    const int k0 = (t & 15) * 2;

    const float gij = M[i * 32 + j];
    const v2f gjk = *(const v2f*)(&M[j * 32 + k0]);     // adjacent, 8B aligned
    v2f gki; gki.x = M[k0 * 32 + i]; gki.y = M[(k0 + 1) * 32 + i];
    v2f acc = (v2f)(0.0f);

    #pragma unroll 4
    for (int h = 0; h < H; ++h) {
        const float4 c = pack[h];
        const float woh = wm2[h];
        const float pre = fmaf(gij, c.y, c.x);
        v2f x = gjk * c.z + (v2f)(pre);     // contracts to v_pk_fma_f32
        x = gki * c.w + x;
        v2f e;
        e.x = __builtin_amdgcn_exp2f(x.x);
        e.y = __builtin_amdgcn_exp2f(x.y);
        e = e + (v2f)(1.0f);                // v_pk_add_f32
        v2f rc;
        rc.x = __builtin_amdgcn_rcpf(e.x);
        rc.y = __builtin_amdgcn_rcpf(e.y);
        acc = rc * woh + acc;               // v_pk_fma_f32
    }

    const float addc = sumw[0] + cb2[0];
    const v2f res = acc + (v2f)(addc);
    *((v2f*)(gamma + ((b * 32 + i) * 32 + j) * 32 + k0)) = res;
}

// ---------------- Stage C: ricci ----------------
// Block = (b,i,jhalf): 16 outputs. Thread = hidden unit h; 33 weights in registers.
// grid = 2048, block = 256
__global__ __launch_bounds__(256) void ricci_kernel(
    const float* __restrict__ metric, const float* __restrict__ rbase,
    const float* __restrict__ rw1, const float* __restrict__ rw2,
    const float* __restrict__ rb2,
    const float* __restrict__ gamma,
    float* __restrict__ out)
{
    __shared__ float Gs[512];           // 16 gamma rows (j-half), 2 KB
    __shared__ float Ms[16];
    __shared__ float red[4][16];
    const int blk = blockIdx.x;
    const int bi  = blk >> 1;           // (b,i)
    const int b   = blk >> 6;
    const int i   = (blk >> 1) & 31;
    const int jh  = blk & 1;
    const int t   = threadIdx.x;

    float w[33];
    #pragma unroll
    for (int f = 0; f < 33; ++f) w[f] = rw1[(32 + f) * 256 + t];
    const float rbv   = rbase[b * 256 + t];
    const float wo    = rw2[t];
    const float rbias = rb2[0];

    ((v2f*)Gs)[t] = ((const v2f*)(gamma + bi * 1024 + jh * 512))[t];
    if (t < 16) Ms[t] = metric[b * 1024 + i * 32 + jh * 16 + t];
    __syncthreads();

    const int wid  = t >> 6;
    const int lane = t & 63;

    for (int jj = 0; jj < 16; ++jj) {
        v2f hidA = (v2f)(0.0f), hidB = (v2f)(0.0f);
        #pragma unroll
        for (int k4 = 0; k4 < 8; ++k4) {
            const float4 g = ((const float4*)Gs)[jj * 8 + k4];
            v2f glo; glo.x = g.x; glo.y = g.y;
            v2f ghi; ghi.x = g.z; ghi.y = g.w;
            v2f wlo; wlo.x = w[k4 * 4 + 1]; wlo.y = w[k4 * 4 + 2];
            v2f whi; whi.x = w[k4 * 4 + 3]; whi.y = w[k4 * 4 + 4];
            hidA = glo * wlo + hidA;        // v_pk_fma_f32
            hidB = ghi * whi + hidB;
        }
        float hid = fmaf(Ms[jj], w[0], rbv) + (hidA.x + hidA.y) + (hidB.x + hidB.y);
        float pp = fmaxf(hid, 0.0f) * wo;
        #pragma unroll
        for (int off = 32; off > 0; off >>= 1) pp += __shfl_xor(pp, off);
        if (lane == 0) red[wid][jj] = pp;
    }
    __syncthreads();
    if (t < 16) out[bi * 32 + jh * 16 + t] = red[0][t] + red[1][t] + red[2][t] + red[3][t] + rbias;
}

extern "C" void kernel_launch(void* const* d_in, const int* in_sizes, int n_in,
                              void* d_out, int out_size, void* d_ws, size_t ws_size,
                              hipStream_t stream) {
    const float* points = (const float*)d_in[0];
    const float* mw1 = (const float*)d_in[1];
    const float* mb1 = (const float*)d_in[2];
    const float* mw2 = (const float*)d_in[3];
    const float* mb2 = (const float*)d_in[4];
    const float* cw1 = (const float*)d_in[5];
    const float* cb1 = (const float*)d_in[6];
    const float* cw2 = (const float*)d_in[7];
    const float* cb2 = (const float*)d_in[8];
    const float* rw1 = (const float*)d_in[9];
    const float* rb1 = (const float*)d_in[10];
    const float* rw2 = (const float*)d_in[11];
    const float* rb2 = (const float*)d_in[12];
    float* out = (float*)d_out;

    char* ws = (char*)d_ws;
    float* metric = (float*)(ws);                      // 32*1024 f32 = 128 KB
    float* cbase  = (float*)(ws + 131072);             // 32*128  f32 = 16 KB
    float* rbase  = (float*)(ws + 147456);             // 32*256  f32 = 32 KB
    float* sumw   = (float*)(ws + 180224);             // 1 f32 (+pad)
    float* gamma  = (float*)(ws + 180480);             // 32*32768 f32 = 4 MB

    setup_kernel<<<32, 256, 0, stream>>>(points, mw1, mb1, mw2, mb2,
                                         cw1, cb1, cw2, rw1, rb1,
                                         metric, cbase, rbase, sumw);
    christoffel_kernel<<<2048, 256, 0, stream>>>(metric, cbase, cw1, cw2, cb2, sumw, gamma);
    ricci_kernel<<<2048, 256, 0, stream>>>(metric, rbase, rw1, rw2, rb2, gamma, out);
}

// Round 5
// 58.527 us; speedup vs baseline: 1.2115x; 1.1179x over previous
//
#include <hip/hip_runtime.h>

#define D 32
#define H 128

typedef float v2f __attribute__((ext_vector_type(2)));

// ---------------- Stage A: metric + folded per-batch constants ----------------
// grid = 32 (one block per batch element), block = 256
__global__ __launch_bounds__(256) void setup_kernel(
    const float* __restrict__ points,
    const float* __restrict__ mw1, const float* __restrict__ mb1,
    const float* __restrict__ mw2, const float* __restrict__ mb2,
    const float* __restrict__ cw1, const float* __restrict__ cb1,
    const float* __restrict__ cw2, const float* __restrict__ cb2,
    const float* __restrict__ rw1, const float* __restrict__ rb1,
    float* __restrict__ metric, float4* __restrict__ cpk4,
    float* __restrict__ rbase, float* __restrict__ wm2, float* __restrict__ cc)
{
    __shared__ float p[D];
    __shared__ float h1[H];
    const int b = blockIdx.x;
    const int t = threadIdx.x;
    if (t < D) p[t] = points[b * D + t];
    __syncthreads();

    if (t < H) {
        float acc = mb1[t];
        #pragma unroll
        for (int d = 0; d < D; ++d) acc = fmaf(p[d], mw1[d * H + t], acc);
        h1[t] = fmaxf(acc, 0.0f);

        constexpr float Kc = 2.8853900817779268f;   // 2*log2(e)
        float cacc = cb1[t];
        #pragma unroll
        for (int d = 0; d < D; ++d) cacc = fmaf(p[d], cw1[d * H + t], cacc);
        cpk4[b * H + t] = make_float4(Kc * cacc,
                                      Kc * cw1[32 * H + t],
                                      Kc * cw1[33 * H + t],
                                      Kc * cw1[34 * H + t]);
        if (b == 0) wm2[t] = -2.0f * cw2[t];
    }
    {
        float racc = rb1[t];
        #pragma unroll
        for (int d = 0; d < D; ++d) racc = fmaf(p[d], rw1[d * 256 + t], racc);
        rbase[b * 256 + t] = racc;
    }
    if (b == 0 && t < 64) {
        float v = cw2[t] + cw2[t + 64];
        #pragma unroll
        for (int off = 32; off > 0; off >>= 1) v += __shfl_xor(v, off);
        if (t == 0) cc[0] = v + cb2[0];
    }
    __syncthreads();

    #pragma unroll
    for (int q = 0; q < 4; ++q) {
        const int m = q * 256 + t;
        float acc = mb2[m];
        for (int h = 0; h < H; ++h) acc = fmaf(h1[h], mw2[h * 1024 + m], acc);
        metric[b * 1024 + m] = acc;
    }
}

// ---------------- Stage B: christoffel, 1M rows ----------------
// Inner loop operands are wave-uniform -> scalar (SMEM) loads into SGPRs.
// Zero LDS traffic in the h-loop; LDS only for the one-time metric tile reads.
// tanh folded: sum_h cw2*tanh = cc + sum_h wm2[h] * rcp(exp2(x)+1).
// 2 rows (adjacent k) per thread, v2f packed. grid = 2048, block = 256.
__global__ __launch_bounds__(256) void christoffel_kernel(
    const float* __restrict__ metric,
    const float4* __restrict__ cpk4, const float* __restrict__ wm2,
    const float* __restrict__ cc,
    float* __restrict__ gamma)
{
    __shared__ float M[D * D];          // metric[b], 4 KB; read once per thread
    const int blk = blockIdx.x;
    const int b   = blk >> 6;
    const int i   = (blk >> 1) & 31;
    const int jh  = blk & 1;
    const int t   = threadIdx.x;

    #pragma unroll
    for (int q = 0; q < 4; ++q) M[q * 256 + t] = metric[b * 1024 + q * 256 + t];
    __syncthreads();

    const int j  = jh * 16 + (t >> 4);
    const int k0 = (t & 15) * 2;

    const float gij = M[i * 32 + j];
    const v2f gjk = *(const v2f*)(&M[j * 32 + k0]);
    v2f gki; gki.x = M[k0 * 32 + i]; gki.y = M[(k0 + 1) * 32 + i];
    v2f acc = (v2f)(0.0f);

    const float4* __restrict__ cp = cpk4 + b * H;   // wave-uniform stream

    #pragma unroll 4
    for (int h = 0; h < H; ++h) {
        const float4 c  = cp[h];        // s_load_dwordx4 (uniform addr)
        const float woh = wm2[h];       // s_load_dword
        const float pre = fmaf(gij, c.y, c.x);
        v2f x = gjk * c.z + (v2f)(pre);     // v_pk_fma_f32
        x = gki * c.w + x;
        v2f e;
        e.x = __builtin_amdgcn_exp2f(x.x);
        e.y = __builtin_amdgcn_exp2f(x.y);
        e = e + (v2f)(1.0f);
        v2f rc;
        rc.x = __builtin_amdgcn_rcpf(e.x);
        rc.y = __builtin_amdgcn_rcpf(e.y);
        acc = rc * woh + acc;
    }

    const v2f res = acc + (v2f)(cc[0]);
    *((v2f*)(gamma + ((b * 32 + i) * 32 + j) * 32 + k0)) = res;
}

// ---------------- Stage C: ricci ----------------
// Block = (b,i,jhalf): 16 outputs. Thread = hidden unit h; 33 weights in VGPRs.
// Gamma rows are wave-uniform -> s_load_dwordx4 stream (no LDS staging at all).
// Paired shuffle reduction: even lanes carry sum(pp0), odd lanes sum(pp1).
// grid = 2048, block = 256
__global__ __launch_bounds__(256) void ricci_kernel(
    const float* __restrict__ metric, const float* __restrict__ rbase,
    const float* __restrict__ rw1, const float* __restrict__ rw2,
    const float* __restrict__ rb2,
    const float* __restrict__ gamma,
    float* __restrict__ out)
{
    __shared__ float red[4][16];
    const int blk = blockIdx.x;
    const int bi  = blk >> 1;           // (b,i)
    const int b   = blk >> 6;
    const int i   = (blk >> 1) & 31;
    const int jh  = blk & 1;
    const int t   = threadIdx.x;

    float w[33];
    #pragma unroll
    for (int f = 0; f < 33; ++f) w[f] = rw1[(32 + f) * 256 + t];
    const float rbv   = rbase[b * 256 + t];
    const float wo    = rw2[t];
    const float rbias = rb2[0];

    const float4* __restrict__ G4   = (const float4*)(gamma + bi * 1024 + jh * 512);
    const float*  __restrict__ Mrow = metric + b * 1024 + i * 32 + jh * 16;

    const int wid  = t >> 6;
    const int lane = t & 63;

    #pragma unroll 2
    for (int jp = 0; jp < 8; ++jp) {
        float pp[2];
        #pragma unroll
        for (int s = 0; s < 2; ++s) {
            const int jj = jp * 2 + s;
            v2f hA = (v2f)(0.0f), hB = (v2f)(0.0f);
            #pragma unroll
            for (int k4 = 0; k4 < 8; ++k4) {
                const float4 g = G4[jj * 8 + k4];   // s_load_dwordx4 (uniform)
                v2f glo; glo.x = g.x; glo.y = g.y;
                v2f ghi; ghi.x = g.z; ghi.y = g.w;
                v2f wlo; wlo.x = w[k4 * 4 + 1]; wlo.y = w[k4 * 4 + 2];
                v2f whi; whi.x = w[k4 * 4 + 3]; whi.y = w[k4 * 4 + 4];
                hA = glo * wlo + hA;
                hB = ghi * whi + hB;
            }
            const float hid = fmaf(Mrow[jj], w[0], rbv) + (hA.x + hA.y) + (hB.x + hB.y);
            pp[s] = fmaxf(hid, 0.0f) * wo;
        }
        // paired reduction: one 6-level tree for two outputs
        const float t0 = pp[0] + __shfl_xor(pp[0], 1);
        const float t1 = pp[1] + __shfl_xor(pp[1], 1);
        float z = (lane & 1) ? t1 : t0;
        #pragma unroll
        for (int off = 2; off < 64; off <<= 1) z += __shfl_xor(z, off);
        if (lane < 2) red[wid][jp * 2 + lane] = z;
    }
    __syncthreads();
    if (t < 16) out[bi * 32 + jh * 16 + t] = red[0][t] + red[1][t] + red[2][t] + red[3][t] + rbias;
}

extern "C" void kernel_launch(void* const* d_in, const int* in_sizes, int n_in,
                              void* d_out, int out_size, void* d_ws, size_t ws_size,
                              hipStream_t stream) {
    const float* points = (const float*)d_in[0];
    const float* mw1 = (const float*)d_in[1];
    const float* mb1 = (const float*)d_in[2];
    const float* mw2 = (const float*)d_in[3];
    const float* mb2 = (const float*)d_in[4];
    const float* cw1 = (const float*)d_in[5];
    const float* cb1 = (const float*)d_in[6];
    const float* cw2 = (const float*)d_in[7];
    const float* cb2 = (const float*)d_in[8];
    const float* rw1 = (const float*)d_in[9];
    const float* rb1 = (const float*)d_in[10];
    const float* rw2 = (const float*)d_in[11];
    const float* rb2 = (const float*)d_in[12];
    float* out = (float*)d_out;

    char* ws = (char*)d_ws;
    float*  metric = (float*)(ws);                 // 32*1024 f32 = 128 KB @ 0
    float4* cpk4   = (float4*)(ws + 131072);       // 32*128 float4 = 64 KB
    float*  rbase  = (float*)(ws + 196608);        // 32*256 f32 = 32 KB
    float*  wm2    = (float*)(ws + 229376);        // 128 f32
    float*  cc     = (float*)(ws + 229888);        // 1 f32
    float*  gamma  = (float*)(ws + 262144);        // 32*32768 f32 = 4 MB

    setup_kernel<<<32, 256, 0, stream>>>(points, mw1, mb1, mw2, mb2,
                                         cw1, cb1, cw2, cb2, rw1, rb1,
                                         metric, cpk4, rbase, wm2, cc);
    christoffel_kernel<<<2048, 256, 0, stream>>>(metric, cpk4, wm2, cc, gamma);
    ricci_kernel<<<2048, 256, 0, stream>>>(metric, rbase, rw1, rw2, rb2, gamma, out);
}

// Round 6
// 55.405 us; speedup vs baseline: 1.2797x; 1.0563x over previous
//
#include <hip/hip_runtime.h>

#define D 32
#define H 128

typedef float v2f __attribute__((ext_vector_type(2)));

// ---------------- Stage A: metric + folded per-batch constants ----------------
// grid = 256: blk = (b, q) ; q = m-chunk of 128 metric outputs. h1 recomputed
// redundantly per block (cheap); side jobs (cpk4/rbase/cc) assigned to chunks.
__global__ __launch_bounds__(256) void setup_kernel(
    const float* __restrict__ points,
    const float* __restrict__ mw1, const float* __restrict__ mb1,
    const float* __restrict__ mw2, const float* __restrict__ mb2,
    const float* __restrict__ cw1, const float* __restrict__ cb1,
    const float* __restrict__ cw2, const float* __restrict__ cb2,
    const float* __restrict__ rw1, const float* __restrict__ rb1,
    float* __restrict__ metric, float4* __restrict__ cpk4,
    float* __restrict__ rbase, float* __restrict__ wm2, float* __restrict__ cc)
{
    __shared__ float p[D];
    __shared__ float h1[H];
    const int blk = blockIdx.x;
    const int b   = blk >> 3;
    const int q   = blk & 7;
    const int t   = threadIdx.x;
    if (t < D) p[t] = points[b * D + t];
    __syncthreads();

    if (t < H) {
        float acc = mb1[t];
        #pragma unroll
        for (int d = 0; d < D; ++d) acc = fmaf(p[d], mw1[d * H + t], acc);
        h1[t] = fmaxf(acc, 0.0f);
    }

    // side jobs, one chunk each
    if (q == 0 && t < H) {
        constexpr float Kc = 2.8853900817779268f;   // 2*log2(e)
        float cacc = cb1[t];
        #pragma unroll
        for (int d = 0; d < D; ++d) cacc = fmaf(p[d], cw1[d * H + t], cacc);
        cpk4[b * H + t] = make_float4(Kc * cacc,
                                      Kc * cw1[32 * H + t],
                                      Kc * cw1[33 * H + t],
                                      Kc * cw1[34 * H + t]);
        if (b == 0) wm2[t] = -2.0f * cw2[t];
    }
    if (q == 1) {
        float racc = rb1[t];
        #pragma unroll
        for (int d = 0; d < D; ++d) racc = fmaf(p[d], rw1[d * 256 + t], racc);
        rbase[b * 256 + t] = racc;
    }
    if (q == 2 && b == 0 && t < 64) {
        float v = cw2[t] + cw2[t + 64];
        #pragma unroll
        for (int off = 32; off > 0; off >>= 1) v += __shfl_xor(v, off);
        if (t == 0) cc[0] = v + cb2[0];
    }
    __syncthreads();

    // metric outputs for this chunk: m = q*128 + t, t < 128
    if (t < 128) {
        const int m = q * 128 + t;
        float acc = mb2[m];
        #pragma unroll 8
        for (int h = 0; h < H; ++h) acc = fmaf(h1[h], mw2[h * 1024 + m], acc);
        metric[b * 1024 + m] = acc;
    }
}

// ---------------- Stage B: christoffel, 1M rows ----------------
// 1 trans per eval: e = exp2(x), then 1/(e+1) via integer-magic + 2 Newton
// iterations (pure pk-FMA). Wave-uniform streams via scalar loads.
// sum_h cw2*tanh = cc + sum_h wm2[h] * rcp(exp2(x)+1).
// 2 rows per thread; grid = 2048, block = 256.
__global__ __launch_bounds__(256) void christoffel_kernel(
    const float* __restrict__ metric,
    const float4* __restrict__ cpk4, const float* __restrict__ wm2,
    const float* __restrict__ cc,
    float* __restrict__ gamma)
{
    __shared__ float M[D * D];          // metric[b], 4 KB; read once per thread
    const int blk = blockIdx.x;
    const int b   = blk >> 6;
    const int i   = (blk >> 1) & 31;
    const int jh  = blk & 1;
    const int t   = threadIdx.x;

    #pragma unroll
    for (int q = 0; q < 4; ++q) M[q * 256 + t] = metric[b * 1024 + q * 256 + t];
    __syncthreads();

    const int j  = jh * 16 + (t >> 4);
    const int k0 = (t & 15) * 2;

    const float gij = M[i * 32 + j];
    const v2f gjk = *(const v2f*)(&M[j * 32 + k0]);
    v2f gki; gki.x = M[k0 * 32 + i]; gki.y = M[(k0 + 1) * 32 + i];
    v2f acc = (v2f)(0.0f);

    const float4* __restrict__ cp = cpk4 + b * H;   // wave-uniform stream

    #pragma unroll 4
    for (int h = 0; h < H; ++h) {
        const float4 c  = cp[h];        // s_load_dwordx4 (uniform addr)
        const float woh = wm2[h];       // s_load_dword
        const float pre = fmaf(gij, c.y, c.x);
        v2f x = gjk * c.z + (v2f)(pre);     // v_pk_fma_f32
        x = gki * c.w + x;
        v2f y;
        y.x = __builtin_amdgcn_exp2f(x.x);  // only trans op per eval
        y.y = __builtin_amdgcn_exp2f(x.y);
        y = y + (v2f)(1.0f);                // y in [1, ~2^15]: normal floats
        // r ~= 1/y : magic seed (max rel err ~5%) + 2 Newton steps -> ~6e-6
        v2f r;
        r.x = __uint_as_float(0x7EF311C3u - __float_as_uint(y.x));
        r.y = __uint_as_float(0x7EF311C3u - __float_as_uint(y.y));
        r = r * ((v2f)(2.0f) - y * r);      // pk_fma(neg) + pk_mul
        r = r * ((v2f)(2.0f) - y * r);
        acc = r * woh + acc;
    }

    const v2f res = acc + (v2f)(cc[0]);
    *((v2f*)(gamma + ((b * 32 + i) * 32 + j) * 32 + k0)) = res;
}

// ---------------- Stage C: ricci ----------------
// Block = (b,i,jhalf): 16 outputs. Thread = hidden unit h; 33 weights in VGPRs.
// Gamma rows wave-uniform -> s_load_dwordx4 stream. Paired shuffle reduction.
// grid = 2048, block = 256
__global__ __launch_bounds__(256) void ricci_kernel(
    const float* __restrict__ metric, const float* __restrict__ rbase,
    const float* __restrict__ rw1, const float* __restrict__ rw2,
    const float* __restrict__ rb2,
    const float* __restrict__ gamma,
    float* __restrict__ out)
{
    __shared__ float red[4][16];
    const int blk = blockIdx.x;
    const int bi  = blk >> 1;           // (b,i)
    const int b   = blk >> 6;
    const int i   = (blk >> 1) & 31;
    const int jh  = blk & 1;
    const int t   = threadIdx.x;

    float w[33];
    #pragma unroll
    for (int f = 0; f < 33; ++f) w[f] = rw1[(32 + f) * 256 + t];
    const float rbv   = rbase[b * 256 + t];
    const float wo    = rw2[t];
    const float rbias = rb2[0];

    const float4* __restrict__ G4   = (const float4*)(gamma + bi * 1024 + jh * 512);
    const float*  __restrict__ Mrow = metric + b * 1024 + i * 32 + jh * 16;

    const int wid  = t >> 6;
    const int lane = t & 63;

    #pragma unroll 2
    for (int jp = 0; jp < 8; ++jp) {
        float pp[2];
        #pragma unroll
        for (int s = 0; s < 2; ++s) {
            const int jj = jp * 2 + s;
            v2f hA = (v2f)(0.0f), hB = (v2f)(0.0f);
            #pragma unroll
            for (int k4 = 0; k4 < 8; ++k4) {
                const float4 g = G4[jj * 8 + k4];   // s_load_dwordx4 (uniform)
                v2f glo; glo.x = g.x; glo.y = g.y;
                v2f ghi; ghi.x = g.z; ghi.y = g.w;
                v2f wlo; wlo.x = w[k4 * 4 + 1]; wlo.y = w[k4 * 4 + 2];
                v2f whi; whi.x = w[k4 * 4 + 3]; whi.y = w[k4 * 4 + 4];
                hA = glo * wlo + hA;
                hB = ghi * whi + hB;
            }
            const float hid = fmaf(Mrow[jj], w[0], rbv) + (hA.x + hA.y) + (hB.x + hB.y);
            pp[s] = fmaxf(hid, 0.0f) * wo;
        }
        const float t0 = pp[0] + __shfl_xor(pp[0], 1);
        const float t1 = pp[1] + __shfl_xor(pp[1], 1);
        float z = (lane & 1) ? t1 : t0;
        #pragma unroll
        for (int off = 2; off < 64; off <<= 1) z += __shfl_xor(z, off);
        if (lane < 2) red[wid][jp * 2 + lane] = z;
    }
    __syncthreads();
    if (t < 16) out[bi * 32 + jh * 16 + t] = red[0][t] + red[1][t] + red[2][t] + red[3][t] + rbias;
}

extern "C" void kernel_launch(void* const* d_in, const int* in_sizes, int n_in,
                              void* d_out, int out_size, void* d_ws, size_t ws_size,
                              hipStream_t stream) {
    const float* points = (const float*)d_in[0];
    const float* mw1 = (const float*)d_in[1];
    const float* mb1 = (const float*)d_in[2];
    const float* mw2 = (const float*)d_in[3];
    const float* mb2 = (const float*)d_in[4];
    const float* cw1 = (const float*)d_in[5];
    const float* cb1 = (const float*)d_in[6];
    const float* cw2 = (const float*)d_in[7];
    const float* cb2 = (const float*)d_in[8];
    const float* rw1 = (const float*)d_in[9];
    const float* rb1 = (const float*)d_in[10];
    const float* rw2 = (const float*)d_in[11];
    const float* rb2 = (const float*)d_in[12];
    float* out = (float*)d_out;

    char* ws = (char*)d_ws;
    float*  metric = (float*)(ws);                 // 32*1024 f32 = 128 KB @ 0
    float4* cpk4   = (float4*)(ws + 131072);       // 32*128 float4 = 64 KB
    float*  rbase  = (float*)(ws + 196608);        // 32*256 f32 = 32 KB
    float*  wm2    = (float*)(ws + 229376);        // 128 f32
    float*  cc     = (float*)(ws + 229888);        // 1 f32
    float*  gamma  = (float*)(ws + 262144);        // 32*32768 f32 = 4 MB

    setup_kernel<<<256, 256, 0, stream>>>(points, mw1, mb1, mw2, mb2,
                                          cw1, cb1, cw2, cb2, rw1, rb1,
                                          metric, cpk4, rbase, wm2, cc);
    christoffel_kernel<<<2048, 256, 0, stream>>>(metric, cpk4, wm2, cc, gamma);
    ricci_kernel<<<2048, 256, 0, stream>>>(metric, rbase, rw1, rw2, rb2, gamma, out);
}

// Round 7
// 54.629 us; speedup vs baseline: 1.2979x; 1.0142x over previous
//
#include <hip/hip_runtime.h>

#define D 32
#define H 128
#define TN 1024           // tanh table entries
#define TRANGE 6.0f       // table covers [-6, 6]

typedef float v2f __attribute__((ext_vector_type(2)));

// ---------------- Stage A: metric + folded per-batch constants ----------------
// grid = 256: blk = (b, q); q = m-chunk of 128 metric outputs. h1 recomputed
// redundantly per block. cpk4 holds table-index-space constants:
// u = S*x + TN/2 = (S*cbase + 512) + (S*a1)gij + (S*a2)gjk + (S*a3)gki
__global__ __launch_bounds__(256) void setup_kernel(
    const float* __restrict__ points,
    const float* __restrict__ mw1, const float* __restrict__ mb1,
    const float* __restrict__ mw2, const float* __restrict__ mb2,
    const float* __restrict__ cw1, const float* __restrict__ cb1,
    const float* __restrict__ rw1, const float* __restrict__ rb1,
    float* __restrict__ metric, float4* __restrict__ cpk4,
    float* __restrict__ rbase)
{
    __shared__ float p[D];
    __shared__ float h1[H];
    const int blk = blockIdx.x;
    const int b   = blk >> 3;
    const int q   = blk & 7;
    const int t   = threadIdx.x;
    if (t < D) p[t] = points[b * D + t];
    __syncthreads();

    if (t < H) {
        float acc = mb1[t];
        #pragma unroll
        for (int d = 0; d < D; ++d) acc = fmaf(p[d], mw1[d * H + t], acc);
        h1[t] = fmaxf(acc, 0.0f);
    }

    if (q == 0 && t < H) {
        constexpr float S = (float)TN / (2.0f * TRANGE);   // 85.3333
        float cacc = cb1[t];
        #pragma unroll
        for (int d = 0; d < D; ++d) cacc = fmaf(p[d], cw1[d * H + t], cacc);
        cpk4[b * H + t] = make_float4(S * cacc + (float)(TN / 2),
                                      S * cw1[32 * H + t],
                                      S * cw1[33 * H + t],
                                      S * cw1[34 * H + t]);
    }
    if (q == 1) {
        float racc = rb1[t];
        #pragma unroll
        for (int d = 0; d < D; ++d) racc = fmaf(p[d], rw1[d * 256 + t], racc);
        rbase[b * 256 + t] = racc;
    }
    __syncthreads();

    if (t < 128) {
        const int m = q * 128 + t;
        float acc = mb2[m];
        #pragma unroll 8
        for (int h = 0; h < H; ++h) acc = fmaf(h1[h], mw2[h * 1024 + m], acc);
        metric[b * 1024 + m] = acc;
    }
}

// ---------------- Stage B: christoffel, 1M rows ----------------
// ZERO transcendentals in the hot loop: tanh via 1024-entry LDS table
// {value, slope}, linear interp (err ~1.3e-5). Index transform folded into
// cpk4 so u comes straight from 2 FMAs. Per eval: ~9 VALU + 1 ds_read_b64.
// Gamma = cb2 + sum_h cw2[h] * tanh_tab(u_h).
// 2 rows per thread; grid = 2048, block = 256.
__global__ __launch_bounds__(256) void christoffel_kernel(
    const float* __restrict__ metric,
    const float4* __restrict__ cpk4, const float* __restrict__ cw2,
    const float* __restrict__ cb2,
    float* __restrict__ gamma)
{
    __shared__ float M[D * D];          // 4 KB
    __shared__ float2 tab[TN];          // 8 KB: {tanh(x_i), tanh(x_{i+1})-tanh(x_i)}
    const int blk = blockIdx.x;
    const int b   = blk >> 6;
    const int i   = (blk >> 1) & 31;
    const int jh  = blk & 1;
    const int t   = threadIdx.x;

    // one-time table fill: 4 entries/thread, 8 exp2 total (cold path)
    constexpr float hstep = 2.0f * TRANGE / (float)TN;
    constexpr float Kc = 2.8853900817779268f;   // 2*log2(e)
    #pragma unroll
    for (int qq = 0; qq < TN / 256; ++qq) {
        const int idx = qq * 256 + t;
        const float x0 = -TRANGE + idx * hstep;
        const float e0 = __builtin_amdgcn_exp2f(Kc * x0);
        const float v0 = 1.0f - 2.0f * __builtin_amdgcn_rcpf(e0 + 1.0f);
        const float e1 = __builtin_amdgcn_exp2f(Kc * (x0 + hstep));
        const float v1 = 1.0f - 2.0f * __builtin_amdgcn_rcpf(e1 + 1.0f);
        tab[idx] = make_float2(v0, v1 - v0);
    }
    #pragma unroll
    for (int qq = 0; qq < 4; ++qq) M[qq * 256 + t] = metric[b * 1024 + qq * 256 + t];
    __syncthreads();

    const int j  = jh * 16 + (t >> 4);
    const int k0 = (t & 15) * 2;

    const float gij = M[i * 32 + j];
    const float gjk0 = M[j * 32 + k0], gjk1 = M[j * 32 + k0 + 1];
    const float gki0 = M[k0 * 32 + i], gki1 = M[(k0 + 1) * 32 + i];
    float acc0 = 0.0f, acc1 = 0.0f;

    const float4* __restrict__ cp = cpk4 + b * H;   // wave-uniform stream

    #pragma unroll 4
    for (int h = 0; h < H; ++h) {
        const float4 c = cp[h];         // uniform -> scalar load
        const float w = cw2[h];         // uniform -> scalar load
        const float pre = fmaf(gij, c.y, c.x);
        float u0 = fmaf(gki0, c.w, fmaf(gjk0, c.z, pre));
        float u1 = fmaf(gki1, c.w, fmaf(gjk1, c.z, pre));
        u0 = fminf(fmaxf(u0, 0.0f), 1023.0f);   // v_med3_f32
        u1 = fminf(fmaxf(u1, 0.0f), 1023.0f);
        const int i0 = (int)u0;
        const int i1 = (int)u1;
        const float fr0 = u0 - (float)i0;
        const float fr1 = u1 - (float)i1;
        const float2 p0 = tab[i0];      // ds_read_b64
        const float2 p1 = tab[i1];
        acc0 = fmaf(fmaf(fr0, p0.y, p0.x), w, acc0);
        acc1 = fmaf(fmaf(fr1, p1.y, p1.x), w, acc1);
    }

    const float bias = cb2[0];
    v2f res; res.x = acc0 + bias; res.y = acc1 + bias;
    *((v2f*)(gamma + ((b * 32 + i) * 32 + j) * 32 + k0)) = res;
}

// ---------------- Stage C: ricci ----------------
// Block = (b,i,jhalf): 16 outputs. Thread = hidden unit h; 33 weights in VGPRs.
// Gamma rows wave-uniform -> scalar load stream. Paired shuffle reduction.
// grid = 2048, block = 256
__global__ __launch_bounds__(256) void ricci_kernel(
    const float* __restrict__ metric, const float* __restrict__ rbase,
    const float* __restrict__ rw1, const float* __restrict__ rw2,
    const float* __restrict__ rb2,
    const float* __restrict__ gamma,
    float* __restrict__ out)
{
    __shared__ float red[4][16];
    const int blk = blockIdx.x;
    const int bi  = blk >> 1;           // (b,i)
    const int b   = blk >> 6;
    const int i   = (blk >> 1) & 31;
    const int jh  = blk & 1;
    const int t   = threadIdx.x;

    float w[33];
    #pragma unroll
    for (int f = 0; f < 33; ++f) w[f] = rw1[(32 + f) * 256 + t];
    const float rbv   = rbase[b * 256 + t];
    const float wo    = rw2[t];
    const float rbias = rb2[0];

    const float4* __restrict__ G4   = (const float4*)(gamma + bi * 1024 + jh * 512);
    const float*  __restrict__ Mrow = metric + b * 1024 + i * 32 + jh * 16;

    const int wid  = t >> 6;
    const int lane = t & 63;

    #pragma unroll 2
    for (int jp = 0; jp < 8; ++jp) {
        float pp[2];
        #pragma unroll
        for (int s = 0; s < 2; ++s) {
            const int jj = jp * 2 + s;
            v2f hA = (v2f)(0.0f), hB = (v2f)(0.0f);
            #pragma unroll
            for (int k4 = 0; k4 < 8; ++k4) {
                const float4 g = G4[jj * 8 + k4];   // uniform -> scalar load
                v2f glo; glo.x = g.x; glo.y = g.y;
                v2f ghi; ghi.x = g.z; ghi.y = g.w;
                v2f wlo; wlo.x = w[k4 * 4 + 1]; wlo.y = w[k4 * 4 + 2];
                v2f whi; whi.x = w[k4 * 4 + 3]; whi.y = w[k4 * 4 + 4];
                hA = glo * wlo + hA;
                hB = ghi * whi + hB;
            }
            const float hid = fmaf(Mrow[jj], w[0], rbv) + (hA.x + hA.y) + (hB.x + hB.y);
            pp[s] = fmaxf(hid, 0.0f) * wo;
        }
        const float t0 = pp[0] + __shfl_xor(pp[0], 1);
        const float t1 = pp[1] + __shfl_xor(pp[1], 1);
        float z = (lane & 1) ? t1 : t0;
        #pragma unroll
        for (int off = 2; off < 64; off <<= 1) z += __shfl_xor(z, off);
        if (lane < 2) red[wid][jp * 2 + lane] = z;
    }
    __syncthreads();
    if (t < 16) out[bi * 32 + jh * 16 + t] = red[0][t] + red[1][t] + red[2][t] + red[3][t] + rbias;
}

extern "C" void kernel_launch(void* const* d_in, const int* in_sizes, int n_in,
                              void* d_out, int out_size, void* d_ws, size_t ws_size,
                              hipStream_t stream) {
    const float* points = (const float*)d_in[0];
    const float* mw1 = (const float*)d_in[1];
    const float* mb1 = (const float*)d_in[2];
    const float* mw2 = (const float*)d_in[3];
    const float* mb2 = (const float*)d_in[4];
    const float* cw1 = (const float*)d_in[5];
    const float* cb1 = (const float*)d_in[6];
    const float* cw2 = (const float*)d_in[7];
    const float* cb2 = (const float*)d_in[8];
    const float* rw1 = (const float*)d_in[9];
    const float* rb1 = (const float*)d_in[10];
    const float* rw2 = (const float*)d_in[11];
    const float* rb2 = (const float*)d_in[12];
    float* out = (float*)d_out;

    char* ws = (char*)d_ws;
    float*  metric = (float*)(ws);                 // 32*1024 f32 = 128 KB @ 0
    float4* cpk4   = (float4*)(ws + 131072);       // 32*128 float4 = 64 KB
    float*  rbase  = (float*)(ws + 196608);        // 32*256 f32 = 32 KB
    float*  gamma  = (float*)(ws + 262144);        // 32*32768 f32 = 4 MB

    setup_kernel<<<256, 256, 0, stream>>>(points, mw1, mb1, mw2, mb2,
                                          cw1, cb1, rw1, rb1,
                                          metric, cpk4, rbase);
    christoffel_kernel<<<2048, 256, 0, stream>>>(metric, cpk4, cw2, cb2, gamma);
    ricci_kernel<<<2048, 256, 0, stream>>>(metric, rbase, rw1, rw2, rb2, gamma, out);
}